// Round 2
// baseline (2865.253 us; speedup 1.0000x reference)
//
#include <hip/hip_runtime.h>

#define DIMX 3072
#define STX 512
#define SIX 1024
#define SQX 1536
#define FFX 12288

typedef __attribute__((ext_vector_type(4))) float f32x4;
typedef __attribute__((ext_vector_type(8))) __bf16 bf16x8;
typedef __attribute__((ext_vector_type(4))) int i32x4;

__device__ __forceinline__ unsigned short f2bf(float f){
  unsigned u = __builtin_bit_cast(unsigned, f);
  u += 0x7FFFu + ((u>>16)&1u);
  return (unsigned short)(u>>16);
}
__device__ __forceinline__ float bf2f(unsigned short h){
  unsigned u = ((unsigned)h)<<16;
  return __builtin_bit_cast(float, u);
}
__device__ __forceinline__ float gelu_tanh(float x){
  float x3 = x*x*x;
  float z = 0.7978845608028654f*(x + 0.044715f*x3);
  z = fminf(fmaxf(z, -15.f), 15.f);
  float e = exp2f(z*2.8853900817779268f);   // e^(2z)
  float th = (e-1.f)/(e+1.f);
  return 0.5f*x*(1.f+th);
}

// ---------------- small kernels ----------------

__global__ void k_silu(const float* __restrict__ temb, float* __restrict__ out){
  int i = blockIdx.x*256 + threadIdx.x;
  if(i < DIMX){
    float x = temb[i];
    out[i] = x / (1.f + exp2f(-x*1.4426950408889634f));
  }
}

// mod layout: mod[mat][j][i], mat in {0=img,1=txt}, j in 0..5, i in 0..3071
__global__ void k_modinit(const float* __restrict__ b_img, const float* __restrict__ b_txt,
                          float* __restrict__ mod){
  int idx = blockIdx.x*256 + threadIdx.x;   // 0..36863
  int mat = idx / 18432; int r = idx % 18432;
  int i = r/6, j = r%6;
  const float* b = mat ? b_txt : b_img;
  mod[mat*18432 + j*3072 + i] = b[r];
}

// grid: 2 mats * 18 col-chunks * 8 k-chunks = 288 blocks of 256
__global__ void k_modgemv(const float* __restrict__ w_img, const float* __restrict__ w_txt,
                          const float* __restrict__ silu_t, float* __restrict__ mod){
  int bz = blockIdx.x;
  int ks = bz & 7; bz >>= 3;
  int nc = bz % 18; int mat = bz / 18;
  const float* W = mat ? w_txt : w_img;
  __shared__ float st[384];
  int k0 = ks*384;
  for(int i = threadIdx.x; i < 384; i += 256) st[i] = silu_t[k0+i];
  __syncthreads();
  int n0 = nc*1024 + threadIdx.x*4;
  float ax=0.f, ay=0.f, az=0.f, aw=0.f;
  const float* Wp = W + (size_t)k0*18432 + n0;
  #pragma unroll 4
  for(int k=0;k<384;k++){
    float4 w = *(const float4*)(Wp + (size_t)k*18432);
    float s = st[k];
    ax += s*w.x; ay += s*w.y; az += s*w.z; aw += s*w.w;
  }
  float* md = mod + mat*18432;
  float vals[4] = {ax, ay, az, aw};
  #pragma unroll
  for(int j=0;j<4;j++){
    int n = n0+j; int i = n/6, jj = n%6;
    atomicAdd(&md[jj*3072 + i], vals[j]);
  }
}

// LayerNorm (no affine) + modulate: out_bf16 = (x-mu)*rstd*(scale+1) + shift
// modp points at shift plane; scale plane at modp+3072
__global__ void k_lnmod(const float* __restrict__ x, const float* __restrict__ modp,
                        unsigned short* __restrict__ out){
  int row = blockIdx.x, t = threadIdx.x;
  const float* xr = x + (size_t)row*DIMX;
  float4 v0 = *(const float4*)(xr + t*4);
  float4 v1 = *(const float4*)(xr + 1024 + t*4);
  float4 v2 = *(const float4*)(xr + 2048 + t*4);
  float s  = v0.x+v0.y+v0.z+v0.w + v1.x+v1.y+v1.z+v1.w + v2.x+v2.y+v2.z+v2.w;
  float s2 = v0.x*v0.x+v0.y*v0.y+v0.z*v0.z+v0.w*v0.w
           + v1.x*v1.x+v1.y*v1.y+v1.z*v1.z+v1.w*v1.w
           + v2.x*v2.x+v2.y*v2.y+v2.z*v2.z+v2.w*v2.w;
  #pragma unroll
  for(int o=32;o>0;o>>=1){ s += __shfl_xor(s,o); s2 += __shfl_xor(s2,o); }
  __shared__ float rs_[4], rs2_[4];
  int wid = t>>6;
  if((t&63)==0){ rs_[wid]=s; rs2_[wid]=s2; }
  __syncthreads();
  float S  = rs_[0]+rs_[1]+rs_[2]+rs_[3];
  float S2 = rs2_[0]+rs2_[1]+rs2_[2]+rs2_[3];
  float mu = S*(1.f/3072.f);
  float var = S2*(1.f/3072.f) - mu*mu;
  float rstd = rsqrtf(var + 1e-6f);
  #pragma unroll
  for(int j=0;j<3;j++){
    int c = j*1024 + t*4;
    float4 sh = *(const float4*)(modp + c);
    float4 sc = *(const float4*)(modp + 3072 + c);
    float4 xv = (j==0)?v0:((j==1)?v1:v2);
    unsigned short h0 = f2bf((xv.x-mu)*rstd*(sc.x+1.f)+sh.x);
    unsigned short h1 = f2bf((xv.y-mu)*rstd*(sc.y+1.f)+sh.y);
    unsigned short h2 = f2bf((xv.z-mu)*rstd*(sc.z+1.f)+sh.z);
    unsigned short h3 = f2bf((xv.w-mu)*rstd*(sc.w+1.f)+sh.w);
    unsigned long long pk = (unsigned long long)(h0 | ((unsigned)h1<<16))
                          | ((unsigned long long)(h2 | ((unsigned)h3<<16))<<32);
    *(unsigned long long*)(out + (size_t)row*DIMX + c) = pk;
  }
}

// RMSNorm(q,k) + RoPE, V passthrough. grid (1536, 24), block 64.
__global__ void k_rmsrope(const unsigned short* __restrict__ qkv_txt,
                          const unsigned short* __restrict__ qkv_img,
                          const float* __restrict__ nqw, const float* __restrict__ nkw,
                          const float* __restrict__ naqw, const float* __restrict__ nakw,
                          const float* __restrict__ cosb, const float* __restrict__ sinb,
                          unsigned short* __restrict__ Q, unsigned short* __restrict__ K,
                          unsigned short* __restrict__ V){
  int s = blockIdx.x, h = blockIdx.y, t = threadIdx.x;
  bool txt = s < STX;
  const unsigned short* src = txt ? (qkv_txt + (size_t)s*9216)
                                  : (qkv_img + (size_t)(s-STX)*9216);
  const float* qw = txt ? naqw : nqw;
  const float* kw = txt ? nakw : nkw;
  int d0 = 2*t;
  float q1 = bf2f(src[h*128 + d0]),        q2 = bf2f(src[h*128 + d0 + 1]);
  float k1 = bf2f(src[3072 + h*128 + d0]), k2 = bf2f(src[3072 + h*128 + d0 + 1]);
  float v1 = bf2f(src[6144 + h*128 + d0]), v2 = bf2f(src[6144 + h*128 + d0 + 1]);
  float sq = q1*q1 + q2*q2, sk = k1*k1 + k2*k2;
  #pragma unroll
  for(int o=32;o>0;o>>=1){ sq += __shfl_xor(sq,o); sk += __shfl_xor(sk,o); }
  float rq = rsqrtf(sq*(1.f/128.f) + 1e-6f);
  float rk = rsqrtf(sk*(1.f/128.f) + 1e-6f);
  q1 *= rq*qw[d0]; q2 *= rq*qw[d0+1];
  k1 *= rk*kw[d0]; k2 *= rk*kw[d0+1];
  float c1 = cosb[(size_t)s*128 + d0], c2 = cosb[(size_t)s*128 + d0 + 1];
  float s1 = sinb[(size_t)s*128 + d0], s2 = sinb[(size_t)s*128 + d0 + 1];
  float Q1 = q1*c1 - q2*s1, Q2 = q2*c2 + q1*s2;
  float K1 = k1*c1 - k2*s1, K2 = k2*c2 + k1*s2;
  size_t o = ((size_t)s*24 + h)*128 + d0;
  Q[o] = f2bf(Q1); Q[o+1] = f2bf(Q2);
  K[o] = f2bf(K1); K[o+1] = f2bf(K2);
  V[o] = f2bf(v1); V[o+1] = f2bf(v2);
}

// V[s][h][d] -> VT[h][d][s]. grid (24 s-tiles, 24 heads), block 256.
__global__ void k_vtrans(const unsigned short* __restrict__ V, unsigned short* __restrict__ VT){
  __shared__ unsigned short tile[64][136];
  int st = blockIdx.x, h = blockIdx.y, t = threadIdx.x;
  int s0 = st*64;
  {
    int s = t>>2;
    #pragma unroll
    for(int i=0;i<4;i++){
      int oct = ((t&3)<<2) + i;     // 0..15 — full 128-wide head dim
      i32x4 d = *(const i32x4*)(V + ((size_t)(s0+s)*24 + h)*128 + oct*8);
      *(i32x4*)&tile[s][oct*8] = d;
    }
  }
  __syncthreads();
  {
    int d0 = t>>3; int strip = t&7;
    #pragma unroll
    for(int i=0;i<4;i++){
      int d = d0 + i*32;
      unsigned short h8[8];
      #pragma unroll
      for(int j=0;j<8;j++) h8[j] = tile[strip*8 + j][d];
      unsigned a0 = h8[0] | ((unsigned)h8[1]<<16);
      unsigned a1 = h8[2] | ((unsigned)h8[3]<<16);
      unsigned a2 = h8[4] | ((unsigned)h8[5]<<16);
      unsigned a3 = h8[6] | ((unsigned)h8[7]<<16);
      i32x4 dv = {(int)a0,(int)a1,(int)a2,(int)a3};
      *(i32x4*)(VT + ((size_t)h*128 + d)*1536 + s0 + strip*8) = dv;
    }
  }
}

// row softmax in place on bf16 rows of length 1536. grid = #rows, block 256.
__global__ void k_softmax(unsigned short* __restrict__ S){
  size_t row = blockIdx.x;
  unsigned short* p = S + row*1536;
  int t = threadIdx.x;
  float v[6];
  float m = -1e30f;
  #pragma unroll
  for(int j=0;j<6;j++){ v[j] = bf2f(p[t + j*256]); m = fmaxf(m, v[j]); }
  #pragma unroll
  for(int o=32;o>0;o>>=1) m = fmaxf(m, __shfl_xor(m, o));
  __shared__ float red[4];
  int wid = t>>6;
  if((t&63)==0) red[wid] = m;
  __syncthreads();
  float M = fmaxf(fmaxf(red[0],red[1]), fmaxf(red[2],red[3]));
  __syncthreads();
  float s = 0.f;
  #pragma unroll
  for(int j=0;j<6;j++){ v[j] = exp2f((v[j]-M)*1.4426950408889634f); s += v[j]; }
  #pragma unroll
  for(int o=32;o>0;o>>=1) s += __shfl_xor(s, o);
  if((t&63)==0) red[wid] = s;
  __syncthreads();
  float inv = 1.f/(red[0]+red[1]+red[2]+red[3]);
  #pragma unroll
  for(int j=0;j<6;j++) p[t + j*256] = f2bf(v[j]*inv);
}

// ---------------- generic MFMA GEMM ----------------
// C[M,N] = epilogue(alpha * A_bf16[M,K] @ B + bias)
// BSRC=0: B = fp32 [K][N] (ldb = N);  BSRC=1: B = bf16 B^T layout [N][K] (ldb)
// mode 0: bf16 out;  mode 1: gelu -> bf16;  mode 2: f32 out = res + gate*(v)
// grid: (N/128, M/128, Z)
template<int BSRC>
__global__ __launch_bounds__(256,2) void k_gemm(
    const unsigned short* __restrict__ A, long lda, long sAz,
    const void* __restrict__ Bp, long ldb, long sBz,
    const float* __restrict__ bias,
    void* __restrict__ Cp, long ldc, long sCz,
    int K, int mode, float alpha,
    const float* __restrict__ res, long ldres,
    const float* __restrict__ gate)
{
  __shared__ unsigned short Als[128][40];
  __shared__ unsigned short Bls[128][40];
  const int t = threadIdx.x;
  const int bn = blockIdx.x, bm = blockIdx.y, bz = blockIdx.z;
  const unsigned short* Ab = A + (size_t)bz*sAz + (size_t)bm*128*lda;
  const float* Wb = nullptr;
  const unsigned short* BTb = nullptr;
  if(BSRC==0) Wb = (const float*)Bp + (size_t)bz*sBz + (size_t)bn*128;
  else        BTb = (const unsigned short*)Bp + (size_t)bz*sBz + (size_t)bn*128*ldb;

  const int lane = t & 63, wid = t>>6, wr = wid>>1, wc = wid&1;
  const int lr = lane & 15, lk = lane>>4;

  f32x4 acc[4][4];
  #pragma unroll
  for(int i=0;i<4;i++)
    #pragma unroll
    for(int j=0;j<4;j++) acc[i][j] = {0.f,0.f,0.f,0.f};

  for(int k0=0;k0<K;k0+=32){
    __syncthreads();
    { // stage A: 128 rows x 32 k (bf16, 16B strips)
      int row = t>>1;
      #pragma unroll
      for(int i=0;i<2;i++){
        int oct = ((t&1)<<1) + i;
        i32x4 d = *(const i32x4*)(Ab + (size_t)row*lda + k0 + oct*8);
        *(i32x4*)&Als[row][oct*8] = d;
      }
    }
    if(BSRC==0){ // stage B from fp32 [K][N]: gather 8 k's per column, convert
      int n = t & 127;
      #pragma unroll
      for(int p=0;p<2;p++){
        int oct = (t>>7) + (p<<1);
        const float* src = Wb + (size_t)(k0 + oct*8)*ldb + n;
        unsigned pk0, pk1, pk2, pk3;
        {
          unsigned short a = f2bf(src[0]),            b = f2bf(src[(size_t)ldb]);
          unsigned short c = f2bf(src[(size_t)2*ldb]), d = f2bf(src[(size_t)3*ldb]);
          pk0 = (unsigned)a | ((unsigned)b<<16);
          pk1 = (unsigned)c | ((unsigned)d<<16);
        }
        {
          unsigned short a = f2bf(src[(size_t)4*ldb]), b = f2bf(src[(size_t)5*ldb]);
          unsigned short c = f2bf(src[(size_t)6*ldb]), d = f2bf(src[(size_t)7*ldb]);
          pk2 = (unsigned)a | ((unsigned)b<<16);
          pk3 = (unsigned)c | ((unsigned)d<<16);
        }
        i32x4 dv = {(int)pk0,(int)pk1,(int)pk2,(int)pk3};
        *(i32x4*)&Bls[n][oct*8] = dv;
      }
    } else { // stage B^T bf16 [N][K]
      int row = t>>1;
      #pragma unroll
      for(int i=0;i<2;i++){
        int oct = ((t&1)<<1) + i;
        i32x4 d = *(const i32x4*)(BTb + (size_t)row*ldb + k0 + oct*8);
        *(i32x4*)&Bls[row][oct*8] = d;
      }
    }
    __syncthreads();
    bf16x8 af[4], bfr[4];
    #pragma unroll
    for(int mf=0;mf<4;mf++) af[mf]  = *(const bf16x8*)&Als[wr*64 + mf*16 + lr][lk*8];
    #pragma unroll
    for(int nf=0;nf<4;nf++) bfr[nf] = *(const bf16x8*)&Bls[wc*64 + nf*16 + lr][lk*8];
    #pragma unroll
    for(int mf=0;mf<4;mf++)
      #pragma unroll
      for(int nf=0;nf<4;nf++)
        acc[mf][nf] = __builtin_amdgcn_mfma_f32_16x16x32_bf16(af[mf], bfr[nf], acc[mf][nf], 0,0,0);
  }

  unsigned short* C16 = (unsigned short*)Cp + (size_t)bz*sCz;
  float* C32 = (float*)Cp + (size_t)bz*sCz;
  #pragma unroll
  for(int mf=0;mf<4;mf++){
    #pragma unroll
    for(int nf=0;nf<4;nf++){
      #pragma unroll
      for(int r=0;r<4;r++){
        size_t row = (size_t)bm*128 + wr*64 + mf*16 + lk*4 + r;
        size_t col = (size_t)bn*128 + wc*64 + nf*16 + lr;
        float v = acc[mf][nf][r]*alpha + (bias ? bias[col] : 0.f);
        if(mode==0){
          C16[row*ldc + col] = f2bf(v);
        } else if(mode==1){
          C16[row*ldc + col] = f2bf(gelu_tanh(v));
        } else {
          C32[row*ldc + col] = res[row*ldres + col] + gate[col]*v;
        }
      }
    }
  }
}

// ---------------- launch ----------------

extern "C" void kernel_launch(void* const* d_in, const int* in_sizes, int n_in,
                              void* d_out, int out_size, void* d_ws, size_t ws_size,
                              hipStream_t stream){
  const float* hidden_states = (const float*)d_in[0];
  const float* enc_states    = (const float*)d_in[1];
  const float* temb          = (const float*)d_in[3];
  const float* rope_cos      = (const float*)d_in[4];
  const float* rope_sin      = (const float*)d_in[5];
  const float* w_img_mod     = (const float*)d_in[6];
  const float* b_img_mod     = (const float*)d_in[7];
  const float* w_txt_mod     = (const float*)d_in[8];
  const float* b_txt_mod     = (const float*)d_in[9];
  const float* norm_q_w      = (const float*)d_in[10];
  const float* norm_k_w      = (const float*)d_in[11];
  const float* norm_aq_w     = (const float*)d_in[12];
  const float* norm_ak_w     = (const float*)d_in[13];
  const float* w_qkv   = (const float*)d_in[14];
  const float* b_qkv   = (const float*)d_in[15];
  const float* w_aqkv  = (const float*)d_in[16];
  const float* b_aqkv  = (const float*)d_in[17];
  const float* w_out_  = (const float*)d_in[18];
  const float* b_out_  = (const float*)d_in[19];
  const float* w_aout  = (const float*)d_in[20];
  const float* b_aout  = (const float*)d_in[21];
  const float* w_mlp1i = (const float*)d_in[22];
  const float* b_mlp1i = (const float*)d_in[23];
  const float* w_mlp2i = (const float*)d_in[24];
  const float* b_mlp2i = (const float*)d_in[25];
  const float* w_mlp1t = (const float*)d_in[26];
  const float* b_mlp1t = (const float*)d_in[27];
  const float* w_mlp2t = (const float*)d_in[28];
  const float* b_mlp2t = (const float*)d_in[29];

  char* ws = (char*)d_ws;
  float* mod    = (float*)(ws + 0);             // 2*6*3072 f32
  float* silu_t = (float*)(ws + 147456);        // 3072 f32
  unsigned short* imgm = (unsigned short*)(ws + 159744);     // 1024x3072 bf16 (also m2)
  unsigned short* txtm = (unsigned short*)(ws + 6451200);    // 512x3072 bf16
  unsigned short* qkvi = (unsigned short*)(ws + 9596928);    // 1024x9216 bf16
  unsigned short* qkvt = (unsigned short*)(ws + 28471296);   // 512x9216 bf16
  unsigned short* Sbuf = (unsigned short*)(ws + 159744);     // 8x1536x1536 bf16 (aliases above, timeline-disjoint)
  unsigned short* mlph = (unsigned short*)(ws + 9596928);    // 1024x12288 bf16 (aliases qkv, timeline-disjoint)
  unsigned short* Qb  = (unsigned short*)(ws + 37908480);    // 1536x24x128 bf16
  unsigned short* Kb  = (unsigned short*)(ws + 47345664);
  unsigned short* Vb  = (unsigned short*)(ws + 56782848);
  unsigned short* VTb = (unsigned short*)(ws + 66220032);    // 24x128x1536 bf16
  unsigned short* attn= (unsigned short*)(ws + 75657216);    // 1536x3072 bf16
  float* hid = (float*)(ws + 85094400);                      // 1024x3072 f32
  float* enc = (float*)(ws + 97677312);                      // 512x3072 f32
  float* out_enc = (float*)d_out;
  float* out_hid = (float*)d_out + (size_t)STX*DIMX;

  // modulation params
  k_silu<<<12,256,0,stream>>>(temb, silu_t);
  k_modinit<<<144,256,0,stream>>>(b_img_mod, b_txt_mod, mod);
  k_modgemv<<<288,256,0,stream>>>(w_img_mod, w_txt_mod, silu_t, mod);

  // LN + modulate (mod1)
  k_lnmod<<<SIX,256,0,stream>>>(hidden_states, mod + 0,     imgm);
  k_lnmod<<<STX,256,0,stream>>>(enc_states,    mod + 18432, txtm);

  // QKV projections
  k_gemm<0><<<dim3(72,8,1),256,0,stream>>>(imgm,3072,0, w_qkv,9216,0, b_qkv,
      qkvi,9216,0, 3072, 0, 1.f, nullptr,0, nullptr);
  k_gemm<0><<<dim3(72,4,1),256,0,stream>>>(txtm,3072,0, w_aqkv,9216,0, b_aqkv,
      qkvt,9216,0, 3072, 0, 1.f, nullptr,0, nullptr);

  // RMS + RoPE -> Q,K,V [1536][24][128]
  k_rmsrope<<<dim3(1536,24),64,0,stream>>>(qkvt, qkvi, norm_q_w, norm_k_w,
      norm_aq_w, norm_ak_w, rope_cos, rope_sin, Qb, Kb, Vb);
  k_vtrans<<<dim3(24,24),256,0,stream>>>(Vb, VTb);

  // attention in 3 groups of 8 heads (S buffer = 37.7MB)
  for(int g=0; g<3; g++){
    long hb = g*8;
    k_gemm<1><<<dim3(12,12,8),256,0,stream>>>(Qb + hb*128, 3072, 128,
        Kb + hb*128, 3072, 128, nullptr,
        Sbuf, 1536, (long)1536*1536, 128, 0, 0.08838834764831845f, nullptr,0,nullptr);
    k_softmax<<<8*1536,256,0,stream>>>(Sbuf);
    k_gemm<1><<<dim3(1,12,8),256,0,stream>>>(Sbuf, 1536, (long)1536*1536,
        VTb + (size_t)hb*128*1536, 1536, (long)128*1536, nullptr,
        attn + hb*128, 3072, 128, 1536, 0, 1.f, nullptr,0,nullptr);
  }

  // output projections with fused residual + gate1
  k_gemm<0><<<dim3(24,4,1),256,0,stream>>>(attn,3072,0, w_aout,3072,0, b_aout,
      enc,3072,0, 3072, 2, 1.f, enc_states,3072, mod + 18432 + 2*3072);
  k_gemm<0><<<dim3(24,8,1),256,0,stream>>>(attn + (size_t)512*3072,3072,0, w_out_,3072,0, b_out_,
      hid,3072,0, 3072, 2, 1.f, hidden_states,3072, mod + 2*3072);

  // img MLP
  k_lnmod<<<SIX,256,0,stream>>>(hid, mod + 3*3072, imgm);
  k_gemm<0><<<dim3(96,8,1),256,0,stream>>>(imgm,3072,0, w_mlp1i,12288,0, b_mlp1i,
      mlph,12288,0, 3072, 1, 1.f, nullptr,0,nullptr);
  k_gemm<0><<<dim3(24,8,1),256,0,stream>>>(mlph,12288,0, w_mlp2i,3072,0, b_mlp2i,
      out_hid,3072,0, 12288, 2, 1.f, hid,3072, mod + 5*3072);

  // txt MLP
  k_lnmod<<<STX,256,0,stream>>>(enc, mod + 18432 + 3*3072, txtm);
  k_gemm<0><<<dim3(96,4,1),256,0,stream>>>(txtm,3072,0, w_mlp1t,12288,0, b_mlp1t,
      mlph,12288,0, 3072, 1, 1.f, nullptr,0,nullptr);
  k_gemm<0><<<dim3(24,4,1),256,0,stream>>>(mlph,12288,0, w_mlp2t,3072,0, b_mlp2t,
      out_enc,3072,0, 12288, 2, 1.f, enc,3072, mod + 18432 + 5*3072);
}

// Round 3
// 1631.680 us; speedup vs baseline: 1.7560x; 1.7560x over previous
//
#include <hip/hip_runtime.h>

#define DIMX 3072
#define STX 512
#define SIX 1024
#define SQX 1536
#define FFX 12288

typedef __attribute__((ext_vector_type(4))) float f32x4;
typedef __attribute__((ext_vector_type(8))) __bf16 bf16x8;
typedef __attribute__((ext_vector_type(4))) int i32x4;

__device__ __forceinline__ unsigned short f2bf(float f){
  unsigned u = __builtin_bit_cast(unsigned, f);
  u += 0x7FFFu + ((u>>16)&1u);
  return (unsigned short)(u>>16);
}
__device__ __forceinline__ float bf2f(unsigned short h){
  unsigned u = ((unsigned)h)<<16;
  return __builtin_bit_cast(float, u);
}
__device__ __forceinline__ float gelu_tanh(float x){
  float x3 = x*x*x;
  float z = 0.7978845608028654f*(x + 0.044715f*x3);
  z = fminf(fmaxf(z, -15.f), 15.f);
  float e = exp2f(z*2.8853900817779268f);   // e^(2z)
  float th = (e-1.f)/(e+1.f);
  return 0.5f*x*(1.f+th);
}

// ---------------- small kernels ----------------

__global__ void k_silu(const float* __restrict__ temb, float* __restrict__ out){
  int i = blockIdx.x*256 + threadIdx.x;
  if(i < DIMX){
    float x = temb[i];
    out[i] = x / (1.f + exp2f(-x*1.4426950408889634f));
  }
}

// mod layout: mod[mat][j][i], mat in {0=img,1=txt}, j in 0..5, i in 0..3071
__global__ void k_modinit(const float* __restrict__ b_img, const float* __restrict__ b_txt,
                          float* __restrict__ mod){
  int idx = blockIdx.x*256 + threadIdx.x;   // 0..36863
  int mat = idx / 18432; int r = idx % 18432;
  int i = r/6, j = r%6;
  const float* b = mat ? b_txt : b_img;
  mod[mat*18432 + j*3072 + i] = b[r];
}

// grid: 2 mats * 18 col-chunks * 8 k-chunks = 288 blocks of 256
__global__ void k_modgemv(const float* __restrict__ w_img, const float* __restrict__ w_txt,
                          const float* __restrict__ silu_t, float* __restrict__ mod){
  int bz = blockIdx.x;
  int ks = bz & 7; bz >>= 3;
  int nc = bz % 18; int mat = bz / 18;
  const float* W = mat ? w_txt : w_img;
  __shared__ float st[384];
  int k0 = ks*384;
  for(int i = threadIdx.x; i < 384; i += 256) st[i] = silu_t[k0+i];
  __syncthreads();
  int n0 = nc*1024 + threadIdx.x*4;
  float ax=0.f, ay=0.f, az=0.f, aw=0.f;
  const float* Wp = W + (size_t)k0*18432 + n0;
  #pragma unroll 4
  for(int k=0;k<384;k++){
    float4 w = *(const float4*)(Wp + (size_t)k*18432);
    float s = st[k];
    ax += s*w.x; ay += s*w.y; az += s*w.z; aw += s*w.w;
  }
  float* md = mod + mat*18432;
  float vals[4] = {ax, ay, az, aw};
  #pragma unroll
  for(int j=0;j<4;j++){
    int n = n0+j; int i = n/6, jj = n%6;
    atomicAdd(&md[jj*3072 + i], vals[j]);
  }
}

// transpose-convert W fp32 [Ktot][Ntot] -> WT bf16 [Ntot][Ktot]
// grid (Ktot/64, Ntot/64), block 256
__global__ void k_wconvT(const float* __restrict__ W, unsigned short* __restrict__ WT,
                         int Ktot, int Ntot){
  __shared__ float tile[64][65];
  int k0 = blockIdx.x*64, n0 = blockIdx.y*64;
  int t = threadIdx.x;
  {
    int r = t>>2;            // local k
    int cb = (t&3)*16;       // local n base
    const float* src = W + (size_t)(k0+r)*Ntot + n0 + cb;
    #pragma unroll
    for(int j=0;j<4;j++){
      float4 v = *(const float4*)(src + 4*j);
      tile[r][cb+4*j+0] = v.x; tile[r][cb+4*j+1] = v.y;
      tile[r][cb+4*j+2] = v.z; tile[r][cb+4*j+3] = v.w;
    }
  }
  __syncthreads();
  {
    int n = t>>2;            // local n
    int kb = (t&3)*16;       // local k base
    unsigned short* dst = WT + (size_t)(n0+n)*Ktot + k0 + kb;
    #pragma unroll
    for(int j2=0;j2<2;j2++){
      unsigned pk[4];
      #pragma unroll
      for(int p=0;p<4;p++){
        int k = kb + j2*8 + p*2;
        unsigned short a = f2bf(tile[k][n]);
        unsigned short b = f2bf(tile[k+1][n]);
        pk[p] = (unsigned)a | ((unsigned)b<<16);
      }
      i32x4 dv = {(int)pk[0],(int)pk[1],(int)pk[2],(int)pk[3]};
      *(i32x4*)(dst + j2*8) = dv;
    }
  }
}

// out[row][col] = res[row][col] + gate[col]*bias[col]; M rows x 3072 cols
__global__ void k_initC(float* __restrict__ out, const float* __restrict__ res,
                        const float* __restrict__ gate, const float* __restrict__ bias){
  int i = (blockIdx.x*256 + threadIdx.x)*4;
  int col = i % 3072;
  float4 r = *(const float4*)(res + i);
  float4 g = *(const float4*)(gate + col);
  float4 b = *(const float4*)(bias + col);
  float4 o = {r.x + g.x*b.x, r.y + g.y*b.y, r.z + g.z*b.z, r.w + g.w*b.w};
  *(float4*)(out + i) = o;
}

// LayerNorm (no affine) + modulate: out_bf16 = (x-mu)*rstd*(scale+1) + shift
__global__ void k_lnmod(const float* __restrict__ x, const float* __restrict__ modp,
                        unsigned short* __restrict__ out){
  int row = blockIdx.x, t = threadIdx.x;
  const float* xr = x + (size_t)row*DIMX;
  float4 v0 = *(const float4*)(xr + t*4);
  float4 v1 = *(const float4*)(xr + 1024 + t*4);
  float4 v2 = *(const float4*)(xr + 2048 + t*4);
  float s  = v0.x+v0.y+v0.z+v0.w + v1.x+v1.y+v1.z+v1.w + v2.x+v2.y+v2.z+v2.w;
  float s2 = v0.x*v0.x+v0.y*v0.y+v0.z*v0.z+v0.w*v0.w
           + v1.x*v1.x+v1.y*v1.y+v1.z*v1.z+v1.w*v1.w
           + v2.x*v2.x+v2.y*v2.y+v2.z*v2.z+v2.w*v2.w;
  #pragma unroll
  for(int o=32;o>0;o>>=1){ s += __shfl_xor(s,o); s2 += __shfl_xor(s2,o); }
  __shared__ float rs_[4], rs2_[4];
  int wid = t>>6;
  if((t&63)==0){ rs_[wid]=s; rs2_[wid]=s2; }
  __syncthreads();
  float S  = rs_[0]+rs_[1]+rs_[2]+rs_[3];
  float S2 = rs2_[0]+rs2_[1]+rs2_[2]+rs2_[3];
  float mu = S*(1.f/3072.f);
  float var = S2*(1.f/3072.f) - mu*mu;
  float rstd = rsqrtf(var + 1e-6f);
  #pragma unroll
  for(int j=0;j<3;j++){
    int c = j*1024 + t*4;
    float4 sh = *(const float4*)(modp + c);
    float4 sc = *(const float4*)(modp + 3072 + c);
    float4 xv = (j==0)?v0:((j==1)?v1:v2);
    unsigned short h0 = f2bf((xv.x-mu)*rstd*(sc.x+1.f)+sh.x);
    unsigned short h1 = f2bf((xv.y-mu)*rstd*(sc.y+1.f)+sh.y);
    unsigned short h2 = f2bf((xv.z-mu)*rstd*(sc.z+1.f)+sh.z);
    unsigned short h3 = f2bf((xv.w-mu)*rstd*(sc.w+1.f)+sh.w);
    unsigned long long pk = (unsigned long long)(h0 | ((unsigned)h1<<16))
                          | ((unsigned long long)(h2 | ((unsigned)h3<<16))<<32);
    *(unsigned long long*)(out + (size_t)row*DIMX + c) = pk;
  }
}

// RMSNorm(q,k) + RoPE, V passthrough. grid (1536, 24), block 64.
__global__ void k_rmsrope(const unsigned short* __restrict__ qkv_txt,
                          const unsigned short* __restrict__ qkv_img,
                          const float* __restrict__ nqw, const float* __restrict__ nkw,
                          const float* __restrict__ naqw, const float* __restrict__ nakw,
                          const float* __restrict__ cosb, const float* __restrict__ sinb,
                          unsigned short* __restrict__ Q, unsigned short* __restrict__ K,
                          unsigned short* __restrict__ V){
  int s = blockIdx.x, h = blockIdx.y, t = threadIdx.x;
  bool txt = s < STX;
  const unsigned short* src = txt ? (qkv_txt + (size_t)s*9216)
                                  : (qkv_img + (size_t)(s-STX)*9216);
  const float* qw = txt ? naqw : nqw;
  const float* kw = txt ? nakw : nkw;
  int d0 = 2*t;
  float q1 = bf2f(src[h*128 + d0]),        q2 = bf2f(src[h*128 + d0 + 1]);
  float k1 = bf2f(src[3072 + h*128 + d0]), k2 = bf2f(src[3072 + h*128 + d0 + 1]);
  float v1 = bf2f(src[6144 + h*128 + d0]), v2 = bf2f(src[6144 + h*128 + d0 + 1]);
  float sq = q1*q1 + q2*q2, sk = k1*k1 + k2*k2;
  #pragma unroll
  for(int o=32;o>0;o>>=1){ sq += __shfl_xor(sq,o); sk += __shfl_xor(sk,o); }
  float rq = rsqrtf(sq*(1.f/128.f) + 1e-6f);
  float rk = rsqrtf(sk*(1.f/128.f) + 1e-6f);
  q1 *= rq*qw[d0]; q2 *= rq*qw[d0+1];
  k1 *= rk*kw[d0]; k2 *= rk*kw[d0+1];
  float c1 = cosb[(size_t)s*128 + d0], c2 = cosb[(size_t)s*128 + d0 + 1];
  float s1 = sinb[(size_t)s*128 + d0], s2 = sinb[(size_t)s*128 + d0 + 1];
  float Q1 = q1*c1 - q2*s1, Q2 = q2*c2 + q1*s2;
  float K1 = k1*c1 - k2*s1, K2 = k2*c2 + k1*s2;
  size_t o = ((size_t)s*24 + h)*128 + d0;
  Q[o] = f2bf(Q1); Q[o+1] = f2bf(Q2);
  K[o] = f2bf(K1); K[o+1] = f2bf(K2);
  V[o] = f2bf(v1); V[o+1] = f2bf(v2);
}

// V[s][h][d] -> VT[h][d][s]. grid (24 s-tiles, 24 heads), block 256.
__global__ void k_vtrans(const unsigned short* __restrict__ V, unsigned short* __restrict__ VT){
  __shared__ unsigned short tile[64][136];
  int st = blockIdx.x, h = blockIdx.y, t = threadIdx.x;
  int s0 = st*64;
  {
    int s = t>>2;
    #pragma unroll
    for(int i=0;i<4;i++){
      int oct = ((t&3)<<2) + i;     // 0..15
      i32x4 d = *(const i32x4*)(V + ((size_t)(s0+s)*24 + h)*128 + oct*8);
      *(i32x4*)&tile[s][oct*8] = d;
    }
  }
  __syncthreads();
  {
    int d0 = t>>3; int strip = t&7;
    #pragma unroll
    for(int i=0;i<4;i++){
      int d = d0 + i*32;
      unsigned short h8[8];
      #pragma unroll
      for(int j=0;j<8;j++) h8[j] = tile[strip*8 + j][d];
      unsigned a0 = h8[0] | ((unsigned)h8[1]<<16);
      unsigned a1 = h8[2] | ((unsigned)h8[3]<<16);
      unsigned a2 = h8[4] | ((unsigned)h8[5]<<16);
      unsigned a3 = h8[6] | ((unsigned)h8[7]<<16);
      i32x4 dv = {(int)a0,(int)a1,(int)a2,(int)a3};
      *(i32x4*)(VT + ((size_t)h*128 + d)*1536 + s0 + strip*8) = dv;
    }
  }
}

// row softmax in place on bf16 rows of length 1536. grid = #rows, block 256.
__global__ void k_softmax(unsigned short* __restrict__ S){
  size_t row = blockIdx.x;
  unsigned short* p = S + row*1536;
  int t = threadIdx.x;
  float v[6];
  float m = -1e30f;
  #pragma unroll
  for(int j=0;j<6;j++){ v[j] = bf2f(p[t + j*256]); m = fmaxf(m, v[j]); }
  #pragma unroll
  for(int o=32;o>0;o>>=1) m = fmaxf(m, __shfl_xor(m, o));
  __shared__ float red[4];
  int wid = t>>6;
  if((t&63)==0) red[wid] = m;
  __syncthreads();
  float M = fmaxf(fmaxf(red[0],red[1]), fmaxf(red[2],red[3]));
  __syncthreads();
  float s = 0.f;
  #pragma unroll
  for(int j=0;j<6;j++){ v[j] = exp2f((v[j]-M)*1.4426950408889634f); s += v[j]; }
  #pragma unroll
  for(int o=32;o>0;o>>=1) s += __shfl_xor(s, o);
  if((t&63)==0) red[wid] = s;
  __syncthreads();
  float inv = 1.f/(red[0]+red[1]+red[2]+red[3]);
  #pragma unroll
  for(int j=0;j<6;j++) p[t + j*256] = f2bf(v[j]*inv);
}

// ---------------- MFMA GEMM, bf16 A (or f32 A), bf16 B^T ----------------
// C[M,N] = epilogue(alpha * A[M,K] @ BT[N,K]^T + bias)
// ASRC=0: A bf16;  ASRC=1: A f32 (converted during staging)
// mode 0: bf16 out (+bias)   mode 1: gelu(v+bias) -> bf16
// mode 3: atomicAdd(C_f32, (gate?gate[col]:1) * alpha*acc)  [bias via k_initC]
// split-K: blockIdx.z = zh*KS + zs; zh indexes slabs (sAz/sBz/sCz), zs the K-chunk
template<int ASRC>
__global__ __launch_bounds__(256,4) void k_gemm(
    const void* __restrict__ Ap, long lda, long sAz,
    const unsigned short* __restrict__ BT, long ldb, long sBz,
    const float* __restrict__ bias,
    void* __restrict__ Cp, long ldc, long sCz,
    int K, int KS, int mode, float alpha,
    const float* __restrict__ gate)
{
  __shared__ unsigned short Als[128][40];
  __shared__ unsigned short Bls[128][40];
  const int t = threadIdx.x;
  const int bn = blockIdx.x, bm = blockIdx.y;
  const int z = blockIdx.z, zh = z / KS, zs = z - zh*KS;
  const int Kc = K / KS, kbeg = zs*Kc, kend = kbeg + Kc;

  const unsigned short* Ab16 = (const unsigned short*)Ap + (size_t)zh*sAz + (size_t)bm*128*lda;
  const float*          Ab32 = (const float*)Ap          + (size_t)zh*sAz + (size_t)bm*128*lda;
  const unsigned short* Bb   = BT + (size_t)zh*sBz + (size_t)bn*128*ldb;

  const int lane = t & 63, wid = t>>6, wr = wid>>1, wc = wid&1;
  const int lr = lane & 15, lk = lane>>4;

  f32x4 acc[4][4];
  #pragma unroll
  for(int i=0;i<4;i++)
    #pragma unroll
    for(int j=0;j<4;j++) acc[i][j] = {0.f,0.f,0.f,0.f};

  const int srow = t>>1;
  const int koff = (t&1)*16;

  for(int k0=kbeg; k0<kend; k0+=32){
    __syncthreads();
    if(ASRC==0){ // A bf16: 128 rows x 32 k, 32B per thread
      i32x4 d0 = *(const i32x4*)(Ab16 + (size_t)srow*lda + k0 + koff);
      i32x4 d1 = *(const i32x4*)(Ab16 + (size_t)srow*lda + k0 + koff + 8);
      *(i32x4*)&Als[srow][koff]     = d0;
      *(i32x4*)&Als[srow][koff + 8] = d1;
    } else {     // A f32: convert 16 floats -> 16 bf16
      const float* src = Ab32 + (size_t)srow*lda + k0 + koff;
      unsigned pk[8];
      #pragma unroll
      for(int p=0;p<4;p++){
        float4 v = *(const float4*)(src + 4*p);
        pk[2*p]   = (unsigned)f2bf(v.x) | ((unsigned)f2bf(v.y)<<16);
        pk[2*p+1] = (unsigned)f2bf(v.z) | ((unsigned)f2bf(v.w)<<16);
      }
      i32x4 d0 = {(int)pk[0],(int)pk[1],(int)pk[2],(int)pk[3]};
      i32x4 d1 = {(int)pk[4],(int)pk[5],(int)pk[6],(int)pk[7]};
      *(i32x4*)&Als[srow][koff]     = d0;
      *(i32x4*)&Als[srow][koff + 8] = d1;
    }
    { // B^T bf16: 128 rows x 32 k
      i32x4 d0 = *(const i32x4*)(Bb + (size_t)srow*ldb + k0 + koff);
      i32x4 d1 = *(const i32x4*)(Bb + (size_t)srow*ldb + k0 + koff + 8);
      *(i32x4*)&Bls[srow][koff]     = d0;
      *(i32x4*)&Bls[srow][koff + 8] = d1;
    }
    __syncthreads();
    bf16x8 af[4], bfr[4];
    #pragma unroll
    for(int mf=0;mf<4;mf++) af[mf]  = *(const bf16x8*)&Als[wr*64 + mf*16 + lr][lk*8];
    #pragma unroll
    for(int nf=0;nf<4;nf++) bfr[nf] = *(const bf16x8*)&Bls[wc*64 + nf*16 + lr][lk*8];
    #pragma unroll
    for(int mf=0;mf<4;mf++)
      #pragma unroll
      for(int nf=0;nf<4;nf++)
        acc[mf][nf] = __builtin_amdgcn_mfma_f32_16x16x32_bf16(af[mf], bfr[nf], acc[mf][nf], 0,0,0);
  }

  unsigned short* C16 = (unsigned short*)Cp + (size_t)zh*sCz;
  float* C32 = (float*)Cp + (size_t)zh*sCz;
  #pragma unroll
  for(int mf=0;mf<4;mf++){
    #pragma unroll
    for(int nf=0;nf<4;nf++){
      #pragma unroll
      for(int r=0;r<4;r++){
        size_t row = (size_t)bm*128 + wr*64 + mf*16 + lk*4 + r;
        size_t col = (size_t)bn*128 + wc*64 + nf*16 + lr;
        float v = acc[mf][nf][r]*alpha;
        if(mode==0){
          C16[row*ldc + col] = f2bf(v + (bias ? bias[col] : 0.f));
        } else if(mode==1){
          C16[row*ldc + col] = f2bf(gelu_tanh(v + (bias ? bias[col] : 0.f)));
        } else {
          float g = gate ? gate[col] : 1.f;
          atomicAdd(&C32[row*ldc + col], g*v);
        }
      }
    }
  }
}

// ---------------- launch ----------------

extern "C" void kernel_launch(void* const* d_in, const int* in_sizes, int n_in,
                              void* d_out, int out_size, void* d_ws, size_t ws_size,
                              hipStream_t stream){
  const float* hidden_states = (const float*)d_in[0];
  const float* enc_states    = (const float*)d_in[1];
  const float* temb          = (const float*)d_in[3];
  const float* rope_cos      = (const float*)d_in[4];
  const float* rope_sin      = (const float*)d_in[5];
  const float* w_img_mod     = (const float*)d_in[6];
  const float* b_img_mod     = (const float*)d_in[7];
  const float* w_txt_mod     = (const float*)d_in[8];
  const float* b_txt_mod     = (const float*)d_in[9];
  const float* norm_q_w      = (const float*)d_in[10];
  const float* norm_k_w      = (const float*)d_in[11];
  const float* norm_aq_w     = (const float*)d_in[12];
  const float* norm_ak_w     = (const float*)d_in[13];
  const float* w_qkv   = (const float*)d_in[14];
  const float* b_qkv   = (const float*)d_in[15];
  const float* w_aqkv  = (const float*)d_in[16];
  const float* b_aqkv  = (const float*)d_in[17];
  const float* w_out_  = (const float*)d_in[18];
  const float* b_out_  = (const float*)d_in[19];
  const float* w_aout  = (const float*)d_in[20];
  const float* b_aout  = (const float*)d_in[21];
  const float* w_mlp1i = (const float*)d_in[22];
  const float* b_mlp1i = (const float*)d_in[23];
  const float* w_mlp2i = (const float*)d_in[24];
  const float* b_mlp2i = (const float*)d_in[25];
  const float* w_mlp1t = (const float*)d_in[26];
  const float* b_mlp1t = (const float*)d_in[27];
  const float* w_mlp2t = (const float*)d_in[28];
  const float* b_mlp2t = (const float*)d_in[29];

  char* ws = (char*)d_ws;
  float* mod    = (float*)(ws + 0);                        // 2*6*3072 f32
  float* silu_t = (float*)(ws + 147456);
  unsigned short* imgm = (unsigned short*)(ws + 159744);   // 1024x3072 bf16
  unsigned short* txtm = (unsigned short*)(ws + 6451200);  // 512x3072 bf16
  float* hid = (float*)(ws + 9596928);                     // 1024x3072 f32
  float* enc = (float*)(ws + 22179840);                    // 512x3072 f32
  float* attnf = (float*)(ws + 28471296);                  // 1536x3072 f32
  unsigned short* Qb  = (unsigned short*)(ws + 47345664);  // 1536x3072 bf16
  unsigned short* Kb  = (unsigned short*)(ws + 56782848);
  unsigned short* Vb  = (unsigned short*)(ws + 66220032);
  unsigned short* VTb = (unsigned short*)(ws + 75657216);  // 24x128x1536 bf16
  // phase-dependent region G at 85094400:
  unsigned short* WT1  = (unsigned short*)(ws + 85094400); // qkv/out weights (<=56.6MB)
  unsigned short* WT1b = (unsigned short*)(ws + 85094400 + 18874368); // 2nd out weight
  unsigned short* Sbuf = (unsigned short*)(ws + 85094400); // 8x1536x1536 bf16 (37.7MB)
  unsigned short* qkvi = (unsigned short*)(ws + 141717504);// 1024x9216 bf16
  unsigned short* qkvt = (unsigned short*)(ws + 160591872);// 512x9216 bf16  (end 170029056)
  // MLP phase (attnf, Q..VT, WT1 all dead):
  unsigned short* WTm  = (unsigned short*)(ws + 28471296); // up to 75.5MB (ends 103968768)
  unsigned short* mlph = (unsigned short*)(ws + 103968768);// 1024x12288 bf16 (ends 129134592)

  float* out_enc = (float*)d_out;
  float* out_hid = (float*)d_out + (size_t)STX*DIMX;

  // modulation params
  k_silu<<<12,256,0,stream>>>(temb, silu_t);
  k_modinit<<<144,256,0,stream>>>(b_img_mod, b_txt_mod, mod);
  k_modgemv<<<288,256,0,stream>>>(w_img_mod, w_txt_mod, silu_t, mod);

  // LN + modulate (mod1)
  k_lnmod<<<SIX,256,0,stream>>>(hidden_states, mod + 0,     imgm);
  k_lnmod<<<STX,256,0,stream>>>(enc_states,    mod + 18432, txtm);

  // QKV projections (weights JIT-converted to bf16 [N][K])
  k_wconvT<<<dim3(48,144),256,0,stream>>>(w_qkv, WT1, 3072, 9216);
  k_gemm<0><<<dim3(72,8,1),256,0,stream>>>(imgm,3072,0, WT1,3072,0, b_qkv,
      qkvi,9216,0, 3072,1, 0, 1.f, nullptr);
  k_wconvT<<<dim3(48,144),256,0,stream>>>(w_aqkv, WT1, 3072, 9216);
  k_gemm<0><<<dim3(72,4,1),256,0,stream>>>(txtm,3072,0, WT1,3072,0, b_aqkv,
      qkvt,9216,0, 3072,1, 0, 1.f, nullptr);

  // RMS + RoPE -> Q,K,V [1536][24][128]; V transpose
  k_rmsrope<<<dim3(1536,24),64,0,stream>>>(qkvt, qkvi, norm_q_w, norm_k_w,
      norm_aq_w, norm_ak_w, rope_cos, rope_sin, Qb, Kb, Vb);
  k_vtrans<<<dim3(24,24),256,0,stream>>>(Vb, VTb);

  // attention: 3 groups of 8 heads; PV split-K(4) atomics into attnf
  hipMemsetAsync(attnf, 0, (size_t)1536*3072*4, stream);
  for(int g=0; g<3; g++){
    long hb = g*8;
    k_gemm<0><<<dim3(12,12,8),256,0,stream>>>(Qb + hb*128, 3072, 128,
        Kb + hb*128, 3072, 128, nullptr,
        Sbuf, 1536, (long)1536*1536, 128,1, 0, 0.08838834764831845f, nullptr);
    k_softmax<<<8*1536,256,0,stream>>>(Sbuf);
    k_gemm<0><<<dim3(1,12,32),256,0,stream>>>(Sbuf, 1536, (long)1536*1536,
        VTb + (size_t)hb*128*1536, 1536, (long)128*1536, nullptr,
        attnf + hb*128, 3072, 128, 1536,4, 3, 1.f, nullptr);
  }

  // output projections, fused residual+gate1, split-K atomics (A is f32 attnf)
  k_wconvT<<<dim3(48,48),256,0,stream>>>(w_aout, WT1, 3072, 3072);
  k_wconvT<<<dim3(48,48),256,0,stream>>>(w_out_, WT1b, 3072, 3072);
  k_initC<<<512*3,256,0,stream>>>(enc, enc_states, mod + 18432 + 2*3072, b_aout);
  k_initC<<<1024*3,256,0,stream>>>(hid, hidden_states, mod + 2*3072, b_out_);
  k_gemm<1><<<dim3(24,4,4),256,0,stream>>>(attnf,3072,0, WT1,3072,0, nullptr,
      enc,3072,0, 3072,4, 3, 1.f, mod + 18432 + 2*3072);
  k_gemm<1><<<dim3(24,8,2),256,0,stream>>>(attnf + (size_t)512*3072,3072,0, WT1b,3072,0, nullptr,
      hid,3072,0, 3072,2, 3, 1.f, mod + 2*3072);

  // img MLP
  k_lnmod<<<SIX,256,0,stream>>>(hid, mod + 3*3072, imgm);
  k_wconvT<<<dim3(48,192),256,0,stream>>>(w_mlp1i, WTm, 3072, 12288);
  k_gemm<0><<<dim3(96,8,1),256,0,stream>>>(imgm,3072,0, WTm,3072,0, b_mlp1i,
      mlph,12288,0, 3072,1, 1, 1.f, nullptr);
  k_wconvT<<<dim3(192,48),256,0,stream>>>(w_mlp2i, WTm, 12288, 3072);
  k_initC<<<1024*3,256,0,stream>>>(out_hid, hid, mod + 5*3072, b_mlp2i);
  k_gemm<0><<<dim3(24,8,2),256,0,stream>>>(mlph,12288,0, WTm,12288,0, nullptr,
      out_hid,3072,0, 12288,2, 3, 1.f, mod + 5*3072);

  // txt MLP
  k_lnmod<<<STX,256,0,stream>>>(enc, mod + 18432 + 3*3072, txtm);
  k_wconvT<<<dim3(48,192),256,0,stream>>>(w_mlp1t, WTm, 3072, 12288);
  k_gemm<0><<<dim3(96,4,1),256,0,stream>>>(txtm,3072,0, WTm,3072,0, b_mlp1t,
      mlph,12288,0, 3072,1, 1, 1.f, nullptr);
  k_wconvT<<<dim3(192,48),256,0,stream>>>(w_mlp2t, WTm, 12288, 3072);
  k_initC<<<512*3,256,0,stream>>>(out_enc, enc, mod + 18432 + 5*3072, b_mlp2t);
  k_gemm<0><<<dim3(24,4,4),256,0,stream>>>(mlph,12288,0, WTm,12288,0, nullptr,
      out_enc,3072,0, 12288,4, 3, 1.f, mod + 18432 + 5*3072);
}

// Round 4
// 1345.331 us; speedup vs baseline: 2.1298x; 1.2128x over previous
//
#include <hip/hip_runtime.h>

#define DIMX 3072
#define STX 512
#define SIX 1024
#define SQX 1536
#define FFX 12288

typedef __attribute__((ext_vector_type(4))) float f32x4;
typedef __attribute__((ext_vector_type(8))) __bf16 bf16x8;
typedef __attribute__((ext_vector_type(4))) int i32x4;

__device__ __forceinline__ unsigned short f2bf(float f){
  unsigned u = __builtin_bit_cast(unsigned, f);
  u += 0x7FFFu + ((u>>16)&1u);
  return (unsigned short)(u>>16);
}
__device__ __forceinline__ float bf2f(unsigned short h){
  unsigned u = ((unsigned)h)<<16;
  return __builtin_bit_cast(float, u);
}
__device__ __forceinline__ float gelu_tanh(float x){
  float x3 = x*x*x;
  float z = 0.7978845608028654f*(x + 0.044715f*x3);
  z = fminf(fmaxf(z, -15.f), 15.f);
  float e = exp2f(z*2.8853900817779268f);   // e^(2z)
  float th = (e-1.f)/(e+1.f);
  return 0.5f*x*(1.f+th);
}

// async global->LDS, 16B per lane; lds base must be wave-uniform
__device__ __forceinline__ void gload16(const unsigned short* g, unsigned short* l){
  __builtin_amdgcn_global_load_lds(
      (const __attribute__((address_space(1))) void*)g,
      (__attribute__((address_space(3))) void*)l,
      16, 0, 0);
}

// ---------------- small kernels ----------------

__global__ void k_silu(const float* __restrict__ temb, float* __restrict__ out){
  int i = blockIdx.x*256 + threadIdx.x;
  if(i < DIMX){
    float x = temb[i];
    out[i] = x / (1.f + exp2f(-x*1.4426950408889634f));
  }
}

// mod layout: mod[mat][j][i], mat in {0=img,1=txt}, j in 0..5, i in 0..3071
__global__ void k_modinit(const float* __restrict__ b_img, const float* __restrict__ b_txt,
                          float* __restrict__ mod){
  int idx = blockIdx.x*256 + threadIdx.x;   // 0..36863
  int mat = idx / 18432; int r = idx % 18432;
  int i = r/6, j = r%6;
  const float* b = mat ? b_txt : b_img;
  mod[mat*18432 + j*3072 + i] = b[r];
}

// grid: 2 mats * 18 col-chunks * 8 k-chunks = 288 blocks of 256
__global__ void k_modgemv(const float* __restrict__ w_img, const float* __restrict__ w_txt,
                          const float* __restrict__ silu_t, float* __restrict__ mod){
  int bz = blockIdx.x;
  int ks = bz & 7; bz >>= 3;
  int nc = bz % 18; int mat = bz / 18;
  const float* W = mat ? w_txt : w_img;
  __shared__ float st[384];
  int k0 = ks*384;
  for(int i = threadIdx.x; i < 384; i += 256) st[i] = silu_t[k0+i];
  __syncthreads();
  int n0 = nc*1024 + threadIdx.x*4;
  float ax=0.f, ay=0.f, az=0.f, aw=0.f;
  const float* Wp = W + (size_t)k0*18432 + n0;
  #pragma unroll 4
  for(int k=0;k<384;k++){
    float4 w = *(const float4*)(Wp + (size_t)k*18432);
    float s = st[k];
    ax += s*w.x; ay += s*w.y; az += s*w.z; aw += s*w.w;
  }
  float* md = mod + mat*18432;
  float vals[4] = {ax, ay, az, aw};
  #pragma unroll
  for(int j=0;j<4;j++){
    int n = n0+j; int i = n/6, jj = n%6;
    atomicAdd(&md[jj*3072 + i], vals[j]);
  }
}

// transpose-convert W fp32 [Ktot][Ntot] -> WT bf16 [Ntot][Ktot]
// grid (Ktot/64, Ntot/64), block 256
__global__ void k_wconvT(const float* __restrict__ W, unsigned short* __restrict__ WT,
                         int Ktot, int Ntot){
  __shared__ float tile[64][65];
  int k0 = blockIdx.x*64, n0 = blockIdx.y*64;
  int t = threadIdx.x;
  {
    int r = t>>2;            // local k
    int cb = (t&3)*16;       // local n base
    const float* src = W + (size_t)(k0+r)*Ntot + n0 + cb;
    #pragma unroll
    for(int j=0;j<4;j++){
      float4 v = *(const float4*)(src + 4*j);
      tile[r][cb+4*j+0] = v.x; tile[r][cb+4*j+1] = v.y;
      tile[r][cb+4*j+2] = v.z; tile[r][cb+4*j+3] = v.w;
    }
  }
  __syncthreads();
  {
    int n = t>>2;            // local n
    int kb = (t&3)*16;       // local k base
    unsigned short* dst = WT + (size_t)(n0+n)*Ktot + k0 + kb;
    #pragma unroll
    for(int j2=0;j2<2;j2++){
      unsigned pk[4];
      #pragma unroll
      for(int p=0;p<4;p++){
        int k = kb + j2*8 + p*2;
        unsigned short a = f2bf(tile[k][n]);
        unsigned short b = f2bf(tile[k+1][n]);
        pk[p] = (unsigned)a | ((unsigned)b<<16);
      }
      i32x4 dv = {(int)pk[0],(int)pk[1],(int)pk[2],(int)pk[3]};
      *(i32x4*)(dst + j2*8) = dv;
    }
  }
}

// out[row][col] = res[row][col] + gate[col]*bias[col]; M rows x 3072 cols
__global__ void k_initC(float* __restrict__ out, const float* __restrict__ res,
                        const float* __restrict__ gate, const float* __restrict__ bias){
  int i = (blockIdx.x*256 + threadIdx.x)*4;
  int col = i % 3072;
  float4 r = *(const float4*)(res + i);
  float4 g = *(const float4*)(gate + col);
  float4 b = *(const float4*)(bias + col);
  float4 o = {r.x + g.x*b.x, r.y + g.y*b.y, r.z + g.z*b.z, r.w + g.w*b.w};
  *(float4*)(out + i) = o;
}

// f32 -> bf16 stream convert (n4 float4 groups)
__global__ void k_f2b(const float* __restrict__ x, unsigned short* __restrict__ y, int n4){
  int i = blockIdx.x*256 + threadIdx.x;
  if(i < n4){
    float4 v = *(const float4*)(x + (size_t)i*4);
    unsigned short h0 = f2bf(v.x), h1 = f2bf(v.y), h2 = f2bf(v.z), h3 = f2bf(v.w);
    unsigned long long pk = (unsigned long long)(h0 | ((unsigned)h1<<16))
                          | ((unsigned long long)(h2 | ((unsigned)h3<<16))<<32);
    *(unsigned long long*)(y + (size_t)i*4) = pk;
  }
}

// LayerNorm (no affine) + modulate: out_bf16 = (x-mu)*rstd*(scale+1) + shift
__global__ void k_lnmod(const float* __restrict__ x, const float* __restrict__ modp,
                        unsigned short* __restrict__ out){
  int row = blockIdx.x, t = threadIdx.x;
  const float* xr = x + (size_t)row*DIMX;
  float4 v0 = *(const float4*)(xr + t*4);
  float4 v1 = *(const float4*)(xr + 1024 + t*4);
  float4 v2 = *(const float4*)(xr + 2048 + t*4);
  float s  = v0.x+v0.y+v0.z+v0.w + v1.x+v1.y+v1.z+v1.w + v2.x+v2.y+v2.z+v2.w;
  float s2 = v0.x*v0.x+v0.y*v0.y+v0.z*v0.z+v0.w*v0.w
           + v1.x*v1.x+v1.y*v1.y+v1.z*v1.z+v1.w*v1.w
           + v2.x*v2.x+v2.y*v2.y+v2.z*v2.z+v2.w*v2.w;
  #pragma unroll
  for(int o=32;o>0;o>>=1){ s += __shfl_xor(s,o); s2 += __shfl_xor(s2,o); }
  __shared__ float rs_[4], rs2_[4];
  int wid = t>>6;
  if((t&63)==0){ rs_[wid]=s; rs2_[wid]=s2; }
  __syncthreads();
  float S  = rs_[0]+rs_[1]+rs_[2]+rs_[3];
  float S2 = rs2_[0]+rs2_[1]+rs2_[2]+rs2_[3];
  float mu = S*(1.f/3072.f);
  float var = S2*(1.f/3072.f) - mu*mu;
  float rstd = rsqrtf(var + 1e-6f);
  #pragma unroll
  for(int j=0;j<3;j++){
    int c = j*1024 + t*4;
    float4 sh = *(const float4*)(modp + c);
    float4 sc = *(const float4*)(modp + 3072 + c);
    float4 xv = (j==0)?v0:((j==1)?v1:v2);
    unsigned short h0 = f2bf((xv.x-mu)*rstd*(sc.x+1.f)+sh.x);
    unsigned short h1 = f2bf((xv.y-mu)*rstd*(sc.y+1.f)+sh.y);
    unsigned short h2 = f2bf((xv.z-mu)*rstd*(sc.z+1.f)+sh.z);
    unsigned short h3 = f2bf((xv.w-mu)*rstd*(sc.w+1.f)+sh.w);
    unsigned long long pk = (unsigned long long)(h0 | ((unsigned)h1<<16))
                          | ((unsigned long long)(h2 | ((unsigned)h3<<16))<<32);
    *(unsigned long long*)(out + (size_t)row*DIMX + c) = pk;
  }
}

// RMSNorm(q,k) + RoPE, V passthrough. grid (1536, 24), block 64.
__global__ void k_rmsrope(const unsigned short* __restrict__ qkv_txt,
                          const unsigned short* __restrict__ qkv_img,
                          const float* __restrict__ nqw, const float* __restrict__ nkw,
                          const float* __restrict__ naqw, const float* __restrict__ nakw,
                          const float* __restrict__ cosb, const float* __restrict__ sinb,
                          unsigned short* __restrict__ Q, unsigned short* __restrict__ K,
                          unsigned short* __restrict__ V){
  int s = blockIdx.x, h = blockIdx.y, t = threadIdx.x;
  bool txt = s < STX;
  const unsigned short* src = txt ? (qkv_txt + (size_t)s*9216)
                                  : (qkv_img + (size_t)(s-STX)*9216);
  const float* qw = txt ? naqw : nqw;
  const float* kw = txt ? nakw : nkw;
  int d0 = 2*t;
  float q1 = bf2f(src[h*128 + d0]),        q2 = bf2f(src[h*128 + d0 + 1]);
  float k1 = bf2f(src[3072 + h*128 + d0]), k2 = bf2f(src[3072 + h*128 + d0 + 1]);
  float v1 = bf2f(src[6144 + h*128 + d0]), v2 = bf2f(src[6144 + h*128 + d0 + 1]);
  float sq = q1*q1 + q2*q2, sk = k1*k1 + k2*k2;
  #pragma unroll
  for(int o=32;o>0;o>>=1){ sq += __shfl_xor(sq,o); sk += __shfl_xor(sk,o); }
  float rq = rsqrtf(sq*(1.f/128.f) + 1e-6f);
  float rk = rsqrtf(sk*(1.f/128.f) + 1e-6f);
  q1 *= rq*qw[d0]; q2 *= rq*qw[d0+1];
  k1 *= rk*kw[d0]; k2 *= rk*kw[d0+1];
  float c1 = cosb[(size_t)s*128 + d0], c2 = cosb[(size_t)s*128 + d0 + 1];
  float s1 = sinb[(size_t)s*128 + d0], s2 = sinb[(size_t)s*128 + d0 + 1];
  float Q1 = q1*c1 - q2*s1, Q2 = q2*c2 + q1*s2;
  float K1 = k1*c1 - k2*s1, K2 = k2*c2 + k1*s2;
  size_t o = ((size_t)s*24 + h)*128 + d0;
  Q[o] = f2bf(Q1); Q[o+1] = f2bf(Q2);
  K[o] = f2bf(K1); K[o+1] = f2bf(K2);
  V[o] = f2bf(v1); V[o+1] = f2bf(v2);
}

// V[s][h][d] -> VT[h][d][s]. grid (24 s-tiles, 24 heads), block 256.
__global__ void k_vtrans(const unsigned short* __restrict__ V, unsigned short* __restrict__ VT){
  __shared__ unsigned short tile[64][136];
  int st = blockIdx.x, h = blockIdx.y, t = threadIdx.x;
  int s0 = st*64;
  {
    int s = t>>2;
    #pragma unroll
    for(int i=0;i<4;i++){
      int oct = ((t&3)<<2) + i;     // 0..15
      i32x4 d = *(const i32x4*)(V + ((size_t)(s0+s)*24 + h)*128 + oct*8);
      *(i32x4*)&tile[s][oct*8] = d;
    }
  }
  __syncthreads();
  {
    int d0 = t>>3; int strip = t&7;
    #pragma unroll
    for(int i=0;i<4;i++){
      int d = d0 + i*32;
      unsigned short h8[8];
      #pragma unroll
      for(int j=0;j<8;j++) h8[j] = tile[strip*8 + j][d];
      unsigned a0 = h8[0] | ((unsigned)h8[1]<<16);
      unsigned a1 = h8[2] | ((unsigned)h8[3]<<16);
      unsigned a2 = h8[4] | ((unsigned)h8[5]<<16);
      unsigned a3 = h8[6] | ((unsigned)h8[7]<<16);
      i32x4 dv = {(int)a0,(int)a1,(int)a2,(int)a3};
      *(i32x4*)(VT + ((size_t)h*128 + d)*1536 + s0 + strip*8) = dv;
    }
  }
}

// row softmax in place on bf16 rows of length 1536. grid = #rows, block 256.
__global__ void k_softmax(unsigned short* __restrict__ S){
  size_t row = blockIdx.x;
  unsigned short* p = S + row*1536;
  int t = threadIdx.x;
  float v[6];
  float m = -1e30f;
  #pragma unroll
  for(int j=0;j<6;j++){ v[j] = bf2f(p[t + j*256]); m = fmaxf(m, v[j]); }
  #pragma unroll
  for(int o=32;o>0;o>>=1) m = fmaxf(m, __shfl_xor(m, o));
  __shared__ float red[4];
  int wid = t>>6;
  if((t&63)==0) red[wid] = m;
  __syncthreads();
  float M = fmaxf(fmaxf(red[0],red[1]), fmaxf(red[2],red[3]));
  __syncthreads();
  float s = 0.f;
  #pragma unroll
  for(int j=0;j<6;j++){ v[j] = exp2f((v[j]-M)*1.4426950408889634f); s += v[j]; }
  #pragma unroll
  for(int o=32;o>0;o>>=1) s += __shfl_xor(s, o);
  if((t&63)==0) red[wid] = s;
  __syncthreads();
  float inv = 1.f/(red[0]+red[1]+red[2]+red[3]);
  #pragma unroll
  for(int j=0;j<6;j++) p[t + j*256] = f2bf(v[j]*inv);
}

// ---------------- MFMA GEMM, bf16 A, bf16 B^T, global_load_lds staging ----------
// C[M,N] = epilogue(alpha * A[M,K] @ BT[N,K]^T + bias)
// mode 0: bf16 out (+bias)   mode 1: gelu(v+bias) -> bf16
// mode 3: atomicAdd(C_f32, (gate?gate[col]:1) * alpha*acc)  [bias via k_initC]
// split-K: blockIdx.z = zh*KS + zs; zh indexes slabs (sAz/sBz/sCz), zs the K-chunk
__global__ __launch_bounds__(256,4) void k_gemm(
    const unsigned short* __restrict__ A, long lda, long sAz,
    const unsigned short* __restrict__ BT, long ldb, long sBz,
    const float* __restrict__ bias,
    void* __restrict__ Cp, long ldc, long sCz,
    int K, int KS, int mode, float alpha,
    const float* __restrict__ gate)
{
  __shared__ unsigned short Als[128*32];
  __shared__ unsigned short Bls[128*32];
  const int t = threadIdx.x;
  const int bn = blockIdx.x, bm = blockIdx.y;
  const int z = blockIdx.z, zh = z / KS, zs = z - zh*KS;
  const int Kc = K / KS, kbeg = zs*Kc, kend = kbeg + Kc;

  const unsigned short* Ab = A  + (size_t)zh*sAz + (size_t)bm*128*lda;
  const unsigned short* Bb = BT + (size_t)zh*sBz + (size_t)bn*128*ldb;

  const int lane = t & 63, wid = t>>6, wr = wid>>1, wc = wid&1;
  const int lr = lane & 15, lk = lane>>4;

  // staging: issue i (0/1), wave w covers rows [i*64 + w*16, +16), lane l:
  // row += l>>2, 16B chunk (l&3). LDS dest = uniform base + lane*16B.
  const int srow = (lane>>2);
  const int soff = (lane&3)*8;

  f32x4 acc[4][4];
  #pragma unroll
  for(int i=0;i<4;i++)
    #pragma unroll
    for(int j=0;j<4;j++) acc[i][j] = {0.f,0.f,0.f,0.f};

  for(int k0=kbeg; k0<kend; k0+=32){
    __syncthreads();
    gload16(Ab + (size_t)(     wid*16 + srow)*lda + k0 + soff, Als + (     wid*16)*32);
    gload16(Ab + (size_t)(64 + wid*16 + srow)*lda + k0 + soff, Als + (64 + wid*16)*32);
    gload16(Bb + (size_t)(     wid*16 + srow)*ldb + k0 + soff, Bls + (     wid*16)*32);
    gload16(Bb + (size_t)(64 + wid*16 + srow)*ldb + k0 + soff, Bls + (64 + wid*16)*32);
    __syncthreads();
    bf16x8 af[4], bfr[4];
    #pragma unroll
    for(int mf=0;mf<4;mf++) af[mf]  = *(const bf16x8*)&Als[(wr*64 + mf*16 + lr)*32 + lk*8];
    #pragma unroll
    for(int nf=0;nf<4;nf++) bfr[nf] = *(const bf16x8*)&Bls[(wc*64 + nf*16 + lr)*32 + lk*8];
    #pragma unroll
    for(int mf=0;mf<4;mf++)
      #pragma unroll
      for(int nf=0;nf<4;nf++)
        acc[mf][nf] = __builtin_amdgcn_mfma_f32_16x16x32_bf16(af[mf], bfr[nf], acc[mf][nf], 0,0,0);
  }

  unsigned short* C16 = (unsigned short*)Cp + (size_t)zh*sCz;
  float* C32 = (float*)Cp + (size_t)zh*sCz;
  #pragma unroll
  for(int mf=0;mf<4;mf++){
    #pragma unroll
    for(int nf=0;nf<4;nf++){
      #pragma unroll
      for(int r=0;r<4;r++){
        size_t row = (size_t)bm*128 + wr*64 + mf*16 + lk*4 + r;
        size_t col = (size_t)bn*128 + wc*64 + nf*16 + lr;
        float v = acc[mf][nf][r]*alpha;
        if(mode==0){
          C16[row*ldc + col] = f2bf(v + (bias ? bias[col] : 0.f));
        } else if(mode==1){
          C16[row*ldc + col] = f2bf(gelu_tanh(v + (bias ? bias[col] : 0.f)));
        } else {
          float g = gate ? gate[col] : 1.f;
          atomicAdd(&C32[row*ldc + col], g*v);
        }
      }
    }
  }
}

// ---------------- launch ----------------

extern "C" void kernel_launch(void* const* d_in, const int* in_sizes, int n_in,
                              void* d_out, int out_size, void* d_ws, size_t ws_size,
                              hipStream_t stream){
  const float* hidden_states = (const float*)d_in[0];
  const float* enc_states    = (const float*)d_in[1];
  const float* temb          = (const float*)d_in[3];
  const float* rope_cos      = (const float*)d_in[4];
  const float* rope_sin      = (const float*)d_in[5];
  const float* w_img_mod     = (const float*)d_in[6];
  const float* b_img_mod     = (const float*)d_in[7];
  const float* w_txt_mod     = (const float*)d_in[8];
  const float* b_txt_mod     = (const float*)d_in[9];
  const float* norm_q_w      = (const float*)d_in[10];
  const float* norm_k_w      = (const float*)d_in[11];
  const float* norm_aq_w     = (const float*)d_in[12];
  const float* norm_ak_w     = (const float*)d_in[13];
  const float* w_qkv   = (const float*)d_in[14];
  const float* b_qkv   = (const float*)d_in[15];
  const float* w_aqkv  = (const float*)d_in[16];
  const float* b_aqkv  = (const float*)d_in[17];
  const float* w_out_  = (const float*)d_in[18];
  const float* b_out_  = (const float*)d_in[19];
  const float* w_aout  = (const float*)d_in[20];
  const float* b_aout  = (const float*)d_in[21];
  const float* w_mlp1i = (const float*)d_in[22];
  const float* b_mlp1i = (const float*)d_in[23];
  const float* w_mlp2i = (const float*)d_in[24];
  const float* b_mlp2i = (const float*)d_in[25];
  const float* w_mlp1t = (const float*)d_in[26];
  const float* b_mlp1t = (const float*)d_in[27];
  const float* w_mlp2t = (const float*)d_in[28];
  const float* b_mlp2t = (const float*)d_in[29];

  char* ws = (char*)d_ws;
  float* mod    = (float*)(ws + 0);                        // 2*6*3072 f32
  float* silu_t = (float*)(ws + 147456);
  unsigned short* imgm = (unsigned short*)(ws + 159744);   // 1024x3072 bf16
  unsigned short* txtm = (unsigned short*)(ws + 6451200);  // 512x3072 bf16
  float* hid = (float*)(ws + 9596928);                     // 1024x3072 f32
  float* enc = (float*)(ws + 22179840);                    // 512x3072 f32
  float* attnf = (float*)(ws + 28471296);                  // 1536x3072 f32 (dead after k_f2b)
  unsigned short* Qb  = (unsigned short*)(ws + 47345664);  // 1536x3072 bf16
  unsigned short* Kb  = (unsigned short*)(ws + 56782848);
  unsigned short* Vb  = (unsigned short*)(ws + 66220032);  // dead after vtrans
  unsigned short* attnb = (unsigned short*)(ws + 66220032);// 1536x3072 bf16 (reuses Vb)
  unsigned short* VTb = (unsigned short*)(ws + 75657216);  // 24x128x1536 bf16
  // phase-dependent region G at 85094400:
  unsigned short* WT1  = (unsigned short*)(ws + 85094400); // qkv weights (56.6MB) / out weight
  unsigned short* WT1b = (unsigned short*)(ws + 85094400 + 18874368); // 2nd out weight
  unsigned short* Sbuf = (unsigned short*)(ws + 85094400); // 8x1536x1536 bf16 (37.7MB)
  unsigned short* qkvi = (unsigned short*)(ws + 141717504);// 1024x9216 bf16
  unsigned short* qkvt = (unsigned short*)(ws + 160591872);// 512x9216 bf16  (end 170029056)
  // MLP phase (attnf, WT1 dead):
  unsigned short* WTm  = (unsigned short*)(ws + 28471296); // up to 75.5MB (ends 103968768)
  unsigned short* mlph = (unsigned short*)(ws + 103968768);// 1024x12288 bf16 (ends 129134592)

  float* out_enc = (float*)d_out;
  float* out_hid = (float*)d_out + (size_t)STX*DIMX;

  // modulation params
  k_silu<<<12,256,0,stream>>>(temb, silu_t);
  k_modinit<<<144,256,0,stream>>>(b_img_mod, b_txt_mod, mod);
  k_modgemv<<<288,256,0,stream>>>(w_img_mod, w_txt_mod, silu_t, mod);

  // LN + modulate (mod1)
  k_lnmod<<<SIX,256,0,stream>>>(hidden_states, mod + 0,     imgm);
  k_lnmod<<<STX,256,0,stream>>>(enc_states,    mod + 18432, txtm);

  // QKV projections (weights JIT-converted to bf16 [N][K])
  k_wconvT<<<dim3(48,144),256,0,stream>>>(w_qkv, WT1, 3072, 9216);
  k_gemm<<<dim3(72,8,1),256,0,stream>>>(imgm,3072,0, WT1,3072,0, b_qkv,
      qkvi,9216,0, 3072,1, 0, 1.f, nullptr);
  k_wconvT<<<dim3(48,144),256,0,stream>>>(w_aqkv, WT1, 3072, 9216);
  k_gemm<<<dim3(72,4,1),256,0,stream>>>(txtm,3072,0, WT1,3072,0, b_aqkv,
      qkvt,9216,0, 3072,1, 0, 1.f, nullptr);

  // RMS + RoPE -> Q,K,V [1536][24][128]; V transpose
  k_rmsrope<<<dim3(1536,24),64,0,stream>>>(qkvt, qkvi, norm_q_w, norm_k_w,
      norm_aq_w, norm_ak_w, rope_cos, rope_sin, Qb, Kb, Vb);
  k_vtrans<<<dim3(24,24),256,0,stream>>>(Vb, VTb);

  // attention: 3 groups of 8 heads; PV split-K(4) atomics into attnf
  hipMemsetAsync(attnf, 0, (size_t)1536*3072*4, stream);
  for(int g=0; g<3; g++){
    long hb = g*8;
    k_gemm<<<dim3(12,12,8),256,0,stream>>>(Qb + hb*128, 3072, 128,
        Kb + hb*128, 3072, 128, nullptr,
        Sbuf, 1536, (long)1536*1536, 128,1, 0, 0.08838834764831845f, nullptr);
    k_softmax<<<8*1536,256,0,stream>>>(Sbuf);
    k_gemm<<<dim3(1,12,32),256,0,stream>>>(Sbuf, 1536, (long)1536*1536,
        VTb + (size_t)hb*128*1536, 1536, (long)128*1536, nullptr,
        attnf + hb*128, 3072, 128, 1536,4, 3, 1.f, nullptr);
  }
  // attn f32 -> bf16 for the out-proj GEMMs
  k_f2b<<<4608,256,0,stream>>>(attnf, attnb, 1536*3072/4);

  // output projections, fused residual+gate1, split-K atomics
  k_wconvT<<<dim3(48,48),256,0,stream>>>(w_aout, WT1, 3072, 3072);
  k_wconvT<<<dim3(48,48),256,0,stream>>>(w_out_, WT1b, 3072, 3072);
  k_initC<<<512*3,256,0,stream>>>(enc, enc_states, mod + 18432 + 2*3072, b_aout);
  k_initC<<<1024*3,256,0,stream>>>(hid, hidden_states, mod + 2*3072, b_out_);
  k_gemm<<<dim3(24,4,4),256,0,stream>>>(attnb,3072,0, WT1,3072,0, nullptr,
      enc,3072,0, 3072,4, 3, 1.f, mod + 18432 + 2*3072);
  k_gemm<<<dim3(24,8,4),256,0,stream>>>(attnb + (size_t)512*3072,3072,0, WT1b,3072,0, nullptr,
      hid,3072,0, 3072,4, 3, 1.f, mod + 2*3072);

  // img MLP
  k_lnmod<<<SIX,256,0,stream>>>(hid, mod + 3*3072, imgm);
  k_wconvT<<<dim3(48,192),256,0,stream>>>(w_mlp1i, WTm, 3072, 12288);
  k_gemm<<<dim3(96,8,1),256,0,stream>>>(imgm,3072,0, WTm,3072,0, b_mlp1i,
      mlph,12288,0, 3072,1, 1, 1.f, nullptr);
  k_wconvT<<<dim3(192,48),256,0,stream>>>(w_mlp2i, WTm, 12288, 3072);
  k_initC<<<1024*3,256,0,stream>>>(out_hid, hid, mod + 5*3072, b_mlp2i);
  k_gemm<<<dim3(24,8,4),256,0,stream>>>(mlph,12288,0, WTm,12288,0, nullptr,
      out_hid,3072,0, 12288,4, 3, 1.f, mod + 5*3072);

  // txt MLP
  k_lnmod<<<STX,256,0,stream>>>(enc, mod + 18432 + 3*3072, txtm);
  k_wconvT<<<dim3(48,192),256,0,stream>>>(w_mlp1t, WTm, 3072, 12288);
  k_gemm<<<dim3(96,4,1),256,0,stream>>>(txtm,3072,0, WTm,3072,0, b_mlp1t,
      mlph,12288,0, 3072,1, 1, 1.f, nullptr);
  k_wconvT<<<dim3(192,48),256,0,stream>>>(w_mlp2t, WTm, 12288, 3072);
  k_initC<<<512*3,256,0,stream>>>(out_enc, enc, mod + 18432 + 5*3072, b_mlp2t);
  k_gemm<<<dim3(24,4,8),256,0,stream>>>(mlph,12288,0, WTm,12288,0, nullptr,
      out_enc,3072,0, 12288,8, 3, 1.f, mod + 18432 + 5*3072);
}